// Round 6
// baseline (544.523 us; speedup 1.0000x reference)
//
#include <hip/hip_runtime.h>

#define NEG 0.01f
#define NBUCK_MAX 512   // buckets of 128 nodes; 50000/128 -> 391 used
#define CHUNK 4096      // edges per partition block
#define CAP 4096        // LDS edge capacity in finalize (avg bucket ~2046)

typedef unsigned int uint;
typedef unsigned short ush;

__device__ __forceinline__ float bf2f(ush u) { return __uint_as_float(((uint)u) << 16); }
__device__ __forceinline__ ush f2bf(float f) {
  uint u = __float_as_uint(f);
  u += 0x7FFFu + ((u >> 16) & 1u);   // RNE
  return (ush)(u >> 16);
}

// ---------------- P0: bucket histogram (LDS-staged) ----------------

__global__ __launch_bounds__(256) void bucket_count(const int* __restrict__ dst,
                                                    int* __restrict__ bcnt, int E) {
  __shared__ int h[NBUCK_MAX];
  int t = threadIdx.x;
  for (int b = t; b < NBUCK_MAX; b += 256) h[b] = 0;
  __syncthreads();
  int base = blockIdx.x * CHUNK;
#pragma unroll
  for (int c = 0; c < CHUNK / 256; ++c) {
    int e = base + c * 256 + t;
    if (e < E) atomicAdd(&h[dst[e] >> 7], 1);
  }
  __syncthreads();
  for (int b = t; b < NBUCK_MAX; b += 256)
    if (h[b]) atomicAdd(&bcnt[b], h[b]);
}

// ---------------- P1: scan 512 bucket counts (1 block) ----------------

__global__ __launch_bounds__(256) void bucket_scan(const int* __restrict__ bcnt,
                                                   int* __restrict__ bbase,
                                                   int* __restrict__ bnext, int E) {
  __shared__ int sc[256];
  int t = threadIdx.x;
  int s0 = bcnt[2 * t], s1 = bcnt[2 * t + 1];
  int p = s0 + s1;
  sc[t] = p;
  __syncthreads();
  for (int off = 1; off < 256; off <<= 1) {
    int v = (t >= off) ? sc[t - off] : 0;
    __syncthreads();
    sc[t] += v;
    __syncthreads();
  }
  int ex = sc[t] - p;
  bbase[2 * t] = ex;
  bbase[2 * t + 1] = ex + s0;
  bnext[2 * t] = ex;
  bnext[2 * t + 1] = ex + s0;
  if (t == 255) bbase[512] = E;
}

// ---------------- P2: partition edges into bucket-grouped tmp (coalesced writes) ----------------

__global__ __launch_bounds__(256) void partition_kernel(const int* __restrict__ src,
                                                        const int* __restrict__ dst,
                                                        int* __restrict__ bnext,
                                                        uint2* __restrict__ tmp, int E) {
  __shared__ int hcnt[NBUCK_MAX];
  __shared__ int hbase[NBUCK_MAX];
  __shared__ int gbase[NBUCK_MAX];
  __shared__ int sc[256];
  __shared__ uint lsrc[CHUNK];
  __shared__ uint ldst[CHUNK];
  int t = threadIdx.x;
  for (int b = t; b < NBUCK_MAX; b += 256) hcnt[b] = 0;
  __syncthreads();
  int base = blockIdx.x * CHUNK;
  uint es[CHUNK / 256], ed[CHUNK / 256];
  int slot[CHUNK / 256];
#pragma unroll
  for (int c = 0; c < CHUNK / 256; ++c) {
    int e = base + c * 256 + t;
    slot[c] = -1;
    if (e < E) {
      es[c] = (uint)src[e];
      ed[c] = (uint)dst[e];
      slot[c] = atomicAdd(&hcnt[ed[c] >> 7], 1);
    }
  }
  __syncthreads();
  int s0 = hcnt[2 * t], s1 = hcnt[2 * t + 1];
  int p = s0 + s1;
  sc[t] = p;
  __syncthreads();
  for (int off = 1; off < 256; off <<= 1) {
    int v = (t >= off) ? sc[t - off] : 0;
    __syncthreads();
    sc[t] += v;
    __syncthreads();
  }
  int ex = sc[t] - p;
  hbase[2 * t] = ex;
  hbase[2 * t + 1] = ex + s0;
  __syncthreads();
#pragma unroll
  for (int c = 0; c < CHUNK / 256; ++c) {
    if (slot[c] >= 0) {
      int pidx = hbase[ed[c] >> 7] + slot[c];
      lsrc[pidx] = es[c];
      ldst[pidx] = ed[c];
    }
  }
  for (int b = t; b < NBUCK_MAX; b += 256)
    if (hcnt[b]) gbase[b] = atomicAdd(&bnext[b], hcnt[b]);
  __syncthreads();
  int m = min(CHUNK, E - base);
  for (int idx = t; idx < m; idx += 256) {
    uint s = lsrc[idx], d = ldst[idx];
    int b = (int)(d >> 7);
    tmp[gbase[b] + (idx - hbase[b])] = make_uint2(s, d);
  }
}

// ---------------- P4: per-bucket CSR finalize: row_ptr, dinv, sorted col ----------------

__global__ __launch_bounds__(256) void csr_finalize(const uint2* __restrict__ tmp,
                                                    const int* __restrict__ bbase,
                                                    int* __restrict__ row_ptr,
                                                    float* __restrict__ dinv,
                                                    int* __restrict__ col, int n, int E) {
  __shared__ int lcnt[128];
  __shared__ int lnxt[128];
  __shared__ int lsc[128];
  __shared__ uint lcol[CAP];
  int b = blockIdx.x;
  int t = threadIdx.x;
  int node0 = b << 7;
  int rp0 = bbase[b], rp1 = bbase[b + 1];
  int m = rp1 - rp0;
  if (t < 128) lcnt[t] = 0;
  __syncthreads();
  for (int idx = t; idx < m; idx += 256)
    atomicAdd(&lcnt[(int)tmp[rp0 + idx].y - node0], 1);
  __syncthreads();
  if (t < 128) lsc[t] = lcnt[t];
  __syncthreads();
  for (int off = 1; off < 128; off <<= 1) {
    int v = 0;
    if (t < 128 && t >= off) v = lsc[t - off];
    __syncthreads();
    if (t < 128) lsc[t] += v;
    __syncthreads();
  }
  if (t < 128) {
    int node = node0 + t;
    int ex = lsc[t] - lcnt[t];
    if (node < n) {
      row_ptr[node] = rp0 + ex;
      dinv[node] = rsqrtf((float)lcnt[t] + 1.0f);  // +1 self-loop
    }
    lnxt[t] = ex;
  }
  if (b == (int)gridDim.x - 1 && t == 0) row_ptr[n] = E;
  __syncthreads();
  if (m <= CAP) {
    for (int idx = t; idx < m; idx += 256) {
      uint2 r = tmp[rp0 + idx];
      int p = atomicAdd(&lnxt[(int)r.y - node0], 1);
      lcol[p] = r.x;
    }
    __syncthreads();
    for (int idx = t; idx < m; idx += 256) col[rp0 + idx] = (int)lcol[idx];
  } else {
    for (int idx = t; idx < m; idx += 256) {
      uint2 r = tmp[rp0 + idx];
      int p = atomicAdd(&lnxt[(int)r.y - node0], 1);
      col[rp0 + p] = (int)r.x;
    }
  }
}

// ---------------- xs = bf16(dinv ⊙ x) ----------------

__global__ __launch_bounds__(256) void xscale_kernel(const float* __restrict__ x,
                                                     const float* __restrict__ dinv,
                                                     ush* __restrict__ xs, int total4) {
  int idx = blockIdx.x * 256 + threadIdx.x;
  if (idx >= total4) return;
  float di = dinv[idx >> 4];
  float4 v = ((const float4*)x)[idx];
  ushort4 o;
  o.x = f2bf(v.x * di);
  o.y = f2bf(v.y * di);
  o.z = f2bf(v.z * di);
  o.w = f2bf(v.w * di);
  ((ushort4*)xs)[idx] = o;
}

// ---------------- Aggregation: 1 wave/node, 16 lanes x bf16x4, 4 edges/instr ----------------
// axs[i,:] = bf16( dinv[i] * ( sum_{s in N(i)} xs[s,:] + xs[i,:] ) )

__global__ __launch_bounds__(256) void aggx_kernel(const ush* __restrict__ xs,
                                                   const float* __restrict__ dinv,
                                                   const int* __restrict__ row_ptr,
                                                   const int* __restrict__ col,
                                                   ush* __restrict__ axs, int n) {
  int lane = threadIdx.x & 63;
  int g = lane >> 4, fl = lane & 15;
  int i = blockIdx.x * 4 + (threadIdx.x >> 6);
  if (i >= n) return;
  int e0 = row_ptr[i], e1 = row_ptr[i + 1];
  float4 acc = make_float4(0.f, 0.f, 0.f, 0.f);
  float4 acc2 = make_float4(0.f, 0.f, 0.f, 0.f);
  int e = e0;
  for (; e + 8 <= e1; e += 8) {
    int c0 = col[e + g], c1 = col[e + 4 + g];
    ushort4 u0 = *(const ushort4*)&xs[(size_t)c0 * 64 + fl * 4];
    ushort4 u1 = *(const ushort4*)&xs[(size_t)c1 * 64 + fl * 4];
    acc.x += bf2f(u0.x);  acc.y += bf2f(u0.y);  acc.z += bf2f(u0.z);  acc.w += bf2f(u0.w);
    acc2.x += bf2f(u1.x); acc2.y += bf2f(u1.y); acc2.z += bf2f(u1.z); acc2.w += bf2f(u1.w);
  }
  for (; e < e1; e += 4) {
    int eg = e + g;
    bool valid = eg < e1;
    int c = col[valid ? eg : e];
    ushort4 u = *(const ushort4*)&xs[(size_t)c * 64 + fl * 4];
    float msk = valid ? 1.f : 0.f;
    acc.x = fmaf(msk, bf2f(u.x), acc.x);
    acc.y = fmaf(msk, bf2f(u.y), acc.y);
    acc.z = fmaf(msk, bf2f(u.z), acc.z);
    acc.w = fmaf(msk, bf2f(u.w), acc.w);
  }
  acc.x += acc2.x; acc.y += acc2.y; acc.z += acc2.z; acc.w += acc2.w;
  acc.x += __shfl_xor(acc.x, 16); acc.y += __shfl_xor(acc.y, 16);
  acc.z += __shfl_xor(acc.z, 16); acc.w += __shfl_xor(acc.w, 16);
  acc.x += __shfl_xor(acc.x, 32); acc.y += __shfl_xor(acc.y, 32);
  acc.z += __shfl_xor(acc.z, 32); acc.w += __shfl_xor(acc.w, 32);
  if (g == 0) {
    ushort4 us = *(const ushort4*)&xs[(size_t)i * 64 + fl * 4];
    float di = dinv[i];
    ushort4 o;
    o.x = f2bf(di * (acc.x + bf2f(us.x)));
    o.y = f2bf(di * (acc.y + bf2f(us.y)));
    o.z = f2bf(di * (acc.z + bf2f(us.z)));
    o.w = f2bf(di * (acc.w + bf2f(us.w)));
    *(ushort4*)&axs[(size_t)i * 64 + fl * 4] = o;
  }
}

// out[i,:] = x[i,:] + b2 + dinv[i] * ( sum h2s[s,:] + h2s[i,:] )
__global__ __launch_bounds__(256) void agg2_kernel(const ush* __restrict__ h2s,
                                                   const float* __restrict__ dinv,
                                                   const int* __restrict__ row_ptr,
                                                   const int* __restrict__ col,
                                                   const float* __restrict__ b,
                                                   const float* __restrict__ x,
                                                   float* __restrict__ out, int n) {
  int lane = threadIdx.x & 63;
  int g = lane >> 4, fl = lane & 15;
  int i = blockIdx.x * 4 + (threadIdx.x >> 6);
  if (i >= n) return;
  int e0 = row_ptr[i], e1 = row_ptr[i + 1];
  float4 acc = make_float4(0.f, 0.f, 0.f, 0.f);
  float4 acc2 = make_float4(0.f, 0.f, 0.f, 0.f);
  int e = e0;
  for (; e + 8 <= e1; e += 8) {
    int c0 = col[e + g], c1 = col[e + 4 + g];
    ushort4 u0 = *(const ushort4*)&h2s[(size_t)c0 * 64 + fl * 4];
    ushort4 u1 = *(const ushort4*)&h2s[(size_t)c1 * 64 + fl * 4];
    acc.x += bf2f(u0.x);  acc.y += bf2f(u0.y);  acc.z += bf2f(u0.z);  acc.w += bf2f(u0.w);
    acc2.x += bf2f(u1.x); acc2.y += bf2f(u1.y); acc2.z += bf2f(u1.z); acc2.w += bf2f(u1.w);
  }
  for (; e < e1; e += 4) {
    int eg = e + g;
    bool valid = eg < e1;
    int c = col[valid ? eg : e];
    ushort4 u = *(const ushort4*)&h2s[(size_t)c * 64 + fl * 4];
    float msk = valid ? 1.f : 0.f;
    acc.x = fmaf(msk, bf2f(u.x), acc.x);
    acc.y = fmaf(msk, bf2f(u.y), acc.y);
    acc.z = fmaf(msk, bf2f(u.z), acc.z);
    acc.w = fmaf(msk, bf2f(u.w), acc.w);
  }
  acc.x += acc2.x; acc.y += acc2.y; acc.z += acc2.z; acc.w += acc2.w;
  acc.x += __shfl_xor(acc.x, 16); acc.y += __shfl_xor(acc.y, 16);
  acc.z += __shfl_xor(acc.z, 16); acc.w += __shfl_xor(acc.w, 16);
  acc.x += __shfl_xor(acc.x, 32); acc.y += __shfl_xor(acc.y, 32);
  acc.z += __shfl_xor(acc.z, 32); acc.w += __shfl_xor(acc.w, 32);
  if (g == 0) {
    ushort4 us = *(const ushort4*)&h2s[(size_t)i * 64 + fl * 4];
    float di = dinv[i];
    float4 xr = *(const float4*)&x[(size_t)i * 64 + fl * 4];
    float4 bb = *(const float4*)&b[fl * 4];
    float4 o;
    o.x = xr.x + bb.x + di * (acc.x + bf2f(us.x));
    o.y = xr.y + bb.y + di * (acc.y + bf2f(us.y));
    o.z = xr.z + bb.z + di * (acc.z + bf2f(us.z));
    o.w = xr.w + bb.w + di * (acc.w + bf2f(us.w));
    *(float4*)&out[(size_t)i * 64 + fl * 4] = o;
  }
}

// ---------------- GEMMs: double-buffered LDS staging, W register-cached ----------------

// y1[n,128] = bf16(leaky(axs[n,64] @ W1[64,128] + b1)); 8 nodes/iter
__global__ __launch_bounds__(256) void gemm1_kernel(const ush* __restrict__ axs,
                                                    const float* __restrict__ W,
                                                    const float* __restrict__ b,
                                                    ush* __restrict__ y1, int n) {
  __shared__ float sx[2][8][64];   // 4 KB
  int t = threadIdx.x;
  int j = t & 127, half = t >> 7;
  float Wreg[64];
#pragma unroll
  for (int k = 0; k < 64; ++k) Wreg[k] = W[k * 128 + j];
  float bj = b[j];
  int ngrp = (n + 7) >> 3;

  auto stage = [&](int g, int buf) {
    if (t < 64) {
      int node = g * 8 + (t >> 3);
      int c = t & 7;
      float* d = &sx[buf][t >> 3][c * 8];
      if (node < n && g < ngrp) {
        ushort4 u0 = *(const ushort4*)&axs[(size_t)node * 64 + c * 8];
        ushort4 u1 = *(const ushort4*)&axs[(size_t)node * 64 + c * 8 + 4];
        d[0] = bf2f(u0.x); d[1] = bf2f(u0.y); d[2] = bf2f(u0.z); d[3] = bf2f(u0.w);
        d[4] = bf2f(u1.x); d[5] = bf2f(u1.y); d[6] = bf2f(u1.z); d[7] = bf2f(u1.w);
      } else {
#pragma unroll
        for (int q = 0; q < 8; ++q) d[q] = 0.f;
      }
    }
  };

  int g = blockIdx.x, buf = 0;
  stage(g, 0);
  for (; g < ngrp; g += gridDim.x) {
    __syncthreads();                 // staged buf visible; prev reads of buf^1 done
    stage(g + gridDim.x, buf ^ 1);   // prefetch next group (hidden under compute)
    int node0 = g * 8 + half * 4;
#pragma unroll
    for (int nn = 0; nn < 4; ++nn) {
      const float4* a4 = (const float4*)sx[buf][half * 4 + nn];
      float acc = 0.f;
#pragma unroll 4
      for (int k4 = 0; k4 < 16; ++k4) {
        float4 a = a4[k4];
        acc = fmaf(a.x, Wreg[k4 * 4 + 0], acc);
        acc = fmaf(a.y, Wreg[k4 * 4 + 1], acc);
        acc = fmaf(a.z, Wreg[k4 * 4 + 2], acc);
        acc = fmaf(a.w, Wreg[k4 * 4 + 3], acc);
      }
      int node = node0 + nn;
      if (node < n) {
        float s = acc + bj;
        s = (s >= 0.f) ? s : NEG * s;
        y1[(size_t)node * 128 + j] = f2bf(s);
      }
    }
    buf ^= 1;
  }
}

// h2s[n,64] = bf16( dinv ⊙ (y1[n,128] @ W2[128,64]) ); 16 nodes/iter
__global__ __launch_bounds__(256) void gemm2_kernel(const ush* __restrict__ y1,
                                                    const float* __restrict__ W,
                                                    const float* __restrict__ dinv,
                                                    ush* __restrict__ h2s, int n) {
  __shared__ float sy[2][16][128];   // 16 KB
  int t = threadIdx.x;
  int j = t & 63, quarter = t >> 6;
  float Wreg[128];
#pragma unroll
  for (int k = 0; k < 128; ++k) Wreg[k] = W[k * 64 + j];
  int ngrp = (n + 15) >> 4;

  auto stage = [&](int g, int buf) {
    int node = g * 16 + (t >> 4);
    int c = t & 15;
    float* d = &sy[buf][t >> 4][c * 8];
    if (node < n && g < ngrp) {
      ushort4 u0 = *(const ushort4*)&y1[(size_t)node * 128 + c * 8];
      ushort4 u1 = *(const ushort4*)&y1[(size_t)node * 128 + c * 8 + 4];
      d[0] = bf2f(u0.x); d[1] = bf2f(u0.y); d[2] = bf2f(u0.z); d[3] = bf2f(u0.w);
      d[4] = bf2f(u1.x); d[5] = bf2f(u1.y); d[6] = bf2f(u1.z); d[7] = bf2f(u1.w);
    } else {
#pragma unroll
      for (int q = 0; q < 8; ++q) d[q] = 0.f;
    }
  };

  int g = blockIdx.x, buf = 0;
  stage(g, 0);
  for (; g < ngrp; g += gridDim.x) {
    __syncthreads();
    stage(g + gridDim.x, buf ^ 1);
    int node0 = g * 16 + quarter * 4;
#pragma unroll
    for (int nn = 0; nn < 4; ++nn) {
      const float4* a4 = (const float4*)sy[buf][quarter * 4 + nn];
      float acc = 0.f;
#pragma unroll 4
      for (int k4 = 0; k4 < 32; ++k4) {
        float4 a = a4[k4];
        acc = fmaf(a.x, Wreg[k4 * 4 + 0], acc);
        acc = fmaf(a.y, Wreg[k4 * 4 + 1], acc);
        acc = fmaf(a.z, Wreg[k4 * 4 + 2], acc);
        acc = fmaf(a.w, Wreg[k4 * 4 + 3], acc);
      }
      int node = node0 + nn;
      if (node < n) h2s[(size_t)node * 64 + j] = f2bf(acc * dinv[node]);
    }
    buf ^= 1;
  }
}

// ---------------- launch ----------------

extern "C" void kernel_launch(void* const* d_in, const int* in_sizes, int n_in,
                              void* d_out, int out_size, void* d_ws, size_t ws_size,
                              hipStream_t stream) {
  const int n = in_sizes[0] / 64;   // 50000
  const int E = in_sizes[5] / 2;    // 800000

  const float* x  = (const float*)d_in[0];
  const float* W1 = (const float*)d_in[1];
  const float* b1 = (const float*)d_in[2];
  const float* W2 = (const float*)d_in[3];
  const float* b2 = (const float*)d_in[4];
  const int* edge = (const int*)d_in[5];
  const int* esrc = edge;
  const int* edst = edge + E;

  char* ws = (char*)d_ws;
  size_t o = 0;
  auto take = [&](size_t bytes) -> void* {
    void* p = ws + o;
    o += (bytes + 255) & ~(size_t)255;
    return p;
  };
  const int NBUCK = (n + 127) >> 7;  // 391
  int*   bcnt    = (int*)take(512 * 4);
  int*   bbase   = (int*)take(513 * 4);
  int*   bnext   = (int*)take(512 * 4);
  int*   row_ptr = (int*)take((size_t)(n + 1) * 4);
  float* dinv    = (float*)take((size_t)n * 4);
  uint2* tmp     = (uint2*)take((size_t)E * 8);
  int*   col     = (int*)take((size_t)E * 4);
  ush*   xs      = (ush*)take((size_t)n * 64 * 2);
  ush*   axs     = (ush*)take((size_t)n * 64 * 2);
  ush*   y1      = (ush*)take((size_t)n * 128 * 2);
  ush*   h2s     = xs;  // xs dead after aggx; reuse

  hipMemsetAsync(bcnt, 0, 512 * 4, stream);

  int pb = (E + CHUNK - 1) / CHUNK;  // 196
  bucket_count<<<pb, 256, 0, stream>>>(edst, bcnt, E);
  bucket_scan<<<1, 256, 0, stream>>>(bcnt, bbase, bnext, E);
  partition_kernel<<<pb, 256, 0, stream>>>(esrc, edst, bnext, tmp, E);
  csr_finalize<<<NBUCK, 256, 0, stream>>>(tmp, bbase, row_ptr, dinv, col, n, E);

  xscale_kernel<<<(n * 16 + 255) / 256, 256, 0, stream>>>(x, dinv, xs, n * 16);
  aggx_kernel<<<(n + 3) / 4, 256, 0, stream>>>(xs, dinv, row_ptr, col, axs, n);
  gemm1_kernel<<<1024, 256, 0, stream>>>(axs, W1, b1, y1, n);
  gemm2_kernel<<<512, 256, 0, stream>>>(y1, W2, dinv, h2s, n);
  agg2_kernel<<<(n + 3) / 4, 256, 0, stream>>>(h2s, dinv, row_ptr, col, b2, x,
                                               (float*)d_out, n);
}

// Round 8
// 129.283 us; speedup vs baseline: 4.2119x; 4.2119x over previous
//
#include <hip/hip_runtime.h>

#define NEG 0.01f
#define NBUCK_MAX 512   // buckets of 128 nodes; 50000/128 -> 391 used
#define CHUNK 4096      // edges per partition block
#define CAP 4096        // LDS edge capacity in finalize (avg bucket ~2046)

typedef unsigned int uint;
typedef unsigned short ush;
typedef __attribute__((ext_vector_type(8))) short bf8v;   // 8 bf16 = 4 VGPRs
typedef __attribute__((ext_vector_type(4))) float f4v;    // MFMA accumulator

__device__ __forceinline__ float bf2f(ush u) { return __uint_as_float(((uint)u) << 16); }
__device__ __forceinline__ ush f2bf(float f) {
  uint u = __float_as_uint(f);
  u += 0x7FFFu + ((u >> 16) & 1u);   // RNE
  return (ush)(u >> 16);
}

// ---------------- P0: bucket histogram (LDS-staged) ----------------

__global__ __launch_bounds__(256) void bucket_count(const int* __restrict__ dst,
                                                    int* __restrict__ bcnt, int E) {
  __shared__ int h[NBUCK_MAX];
  int t = threadIdx.x;
  for (int b = t; b < NBUCK_MAX; b += 256) h[b] = 0;
  __syncthreads();
  int base = blockIdx.x * CHUNK;
#pragma unroll
  for (int c = 0; c < CHUNK / 256; ++c) {
    int e = base + c * 256 + t;
    if (e < E) atomicAdd(&h[dst[e] >> 7], 1);
  }
  __syncthreads();
  for (int b = t; b < NBUCK_MAX; b += 256)
    if (h[b]) atomicAdd(&bcnt[b], h[b]);
}

// ---------------- P1: scan 512 bucket counts (1 block) ----------------

__global__ __launch_bounds__(256) void bucket_scan(const int* __restrict__ bcnt,
                                                   int* __restrict__ bbase,
                                                   int* __restrict__ bnext, int E) {
  __shared__ int sc[256];
  int t = threadIdx.x;
  int s0 = bcnt[2 * t], s1 = bcnt[2 * t + 1];
  int p = s0 + s1;
  sc[t] = p;
  __syncthreads();
  for (int off = 1; off < 256; off <<= 1) {
    int v = (t >= off) ? sc[t - off] : 0;
    __syncthreads();
    sc[t] += v;
    __syncthreads();
  }
  int ex = sc[t] - p;
  bbase[2 * t] = ex;
  bbase[2 * t + 1] = ex + s0;
  bnext[2 * t] = ex;
  bnext[2 * t + 1] = ex + s0;
  if (t == 255) bbase[512] = E;
}

// ---------------- P2: partition edges into bucket-grouped tmp (coalesced writes) ----------------

__global__ __launch_bounds__(256) void partition_kernel(const int* __restrict__ src,
                                                        const int* __restrict__ dst,
                                                        int* __restrict__ bnext,
                                                        uint2* __restrict__ tmp, int E) {
  __shared__ int hcnt[NBUCK_MAX];
  __shared__ int hbase[NBUCK_MAX];
  __shared__ int gbase[NBUCK_MAX];
  __shared__ int sc[256];
  __shared__ uint lsrc[CHUNK];
  __shared__ uint ldst[CHUNK];
  int t = threadIdx.x;
  for (int b = t; b < NBUCK_MAX; b += 256) hcnt[b] = 0;
  __syncthreads();
  int base = blockIdx.x * CHUNK;
  uint es[CHUNK / 256], ed[CHUNK / 256];
  int slot[CHUNK / 256];
#pragma unroll
  for (int c = 0; c < CHUNK / 256; ++c) {
    int e = base + c * 256 + t;
    slot[c] = -1;
    if (e < E) {
      es[c] = (uint)src[e];
      ed[c] = (uint)dst[e];
      slot[c] = atomicAdd(&hcnt[ed[c] >> 7], 1);
    }
  }
  __syncthreads();
  int s0 = hcnt[2 * t], s1 = hcnt[2 * t + 1];
  int p = s0 + s1;
  sc[t] = p;
  __syncthreads();
  for (int off = 1; off < 256; off <<= 1) {
    int v = (t >= off) ? sc[t - off] : 0;
    __syncthreads();
    sc[t] += v;
    __syncthreads();
  }
  int ex = sc[t] - p;
  hbase[2 * t] = ex;
  hbase[2 * t + 1] = ex + s0;
  __syncthreads();
#pragma unroll
  for (int c = 0; c < CHUNK / 256; ++c) {
    if (slot[c] >= 0) {
      int pidx = hbase[ed[c] >> 7] + slot[c];
      lsrc[pidx] = es[c];
      ldst[pidx] = ed[c];
    }
  }
  for (int b = t; b < NBUCK_MAX; b += 256)
    if (hcnt[b]) gbase[b] = atomicAdd(&bnext[b], hcnt[b]);
  __syncthreads();
  int m = min(CHUNK, E - base);
  for (int idx = t; idx < m; idx += 256) {
    uint s = lsrc[idx], d = ldst[idx];
    int b = (int)(d >> 7);
    tmp[gbase[b] + (idx - hbase[b])] = make_uint2(s, d);
  }
}

// ---------------- P4: per-bucket CSR finalize: row_ptr, dinv, sorted col ----------------

__global__ __launch_bounds__(256) void csr_finalize(const uint2* __restrict__ tmp,
                                                    const int* __restrict__ bbase,
                                                    int* __restrict__ row_ptr,
                                                    float* __restrict__ dinv,
                                                    int* __restrict__ col, int n, int E) {
  __shared__ int lcnt[128];
  __shared__ int lnxt[128];
  __shared__ int lsc[128];
  __shared__ uint lcol[CAP];
  int b = blockIdx.x;
  int t = threadIdx.x;
  int node0 = b << 7;
  int rp0 = bbase[b], rp1 = bbase[b + 1];
  int m = rp1 - rp0;
  if (t < 128) lcnt[t] = 0;
  __syncthreads();
  for (int idx = t; idx < m; idx += 256)
    atomicAdd(&lcnt[(int)tmp[rp0 + idx].y - node0], 1);
  __syncthreads();
  if (t < 128) lsc[t] = lcnt[t];
  __syncthreads();
  for (int off = 1; off < 128; off <<= 1) {
    int v = 0;
    if (t < 128 && t >= off) v = lsc[t - off];
    __syncthreads();
    if (t < 128) lsc[t] += v;
    __syncthreads();
  }
  if (t < 128) {
    int node = node0 + t;
    int ex = lsc[t] - lcnt[t];
    if (node < n) {
      row_ptr[node] = rp0 + ex;
      dinv[node] = rsqrtf((float)lcnt[t] + 1.0f);  // +1 self-loop
    }
    lnxt[t] = ex;
  }
  if (b == (int)gridDim.x - 1 && t == 0) row_ptr[n] = E;
  __syncthreads();
  if (m <= CAP) {
    for (int idx = t; idx < m; idx += 256) {
      uint2 r = tmp[rp0 + idx];
      int p = atomicAdd(&lnxt[(int)r.y - node0], 1);
      lcol[p] = r.x;
    }
    __syncthreads();
    for (int idx = t; idx < m; idx += 256) col[rp0 + idx] = (int)lcol[idx];
  } else {
    for (int idx = t; idx < m; idx += 256) {
      uint2 r = tmp[rp0 + idx];
      int p = atomicAdd(&lnxt[(int)r.y - node0], 1);
      col[rp0 + p] = (int)r.x;
    }
  }
}

// ---------------- xs = bf16(dinv ⊙ x) ----------------

__global__ __launch_bounds__(256) void xscale_kernel(const float* __restrict__ x,
                                                     const float* __restrict__ dinv,
                                                     ush* __restrict__ xs, int total4) {
  int idx = blockIdx.x * 256 + threadIdx.x;
  if (idx >= total4) return;
  float di = dinv[idx >> 4];
  float4 v = ((const float4*)x)[idx];
  ushort4 o;
  o.x = f2bf(v.x * di);
  o.y = f2bf(v.y * di);
  o.z = f2bf(v.z * di);
  o.w = f2bf(v.w * di);
  ((ushort4*)xs)[idx] = o;
}

// ---------------- Aggregation: 1 wave/node, 16 lanes x bf16x4, 4 edges/instr ----------------
// axs[i,:] = bf16( dinv[i] * ( sum_{s in N(i)} xs[s,:] + xs[i,:] ) )

__global__ __launch_bounds__(256) void aggx_kernel(const ush* __restrict__ xs,
                                                   const float* __restrict__ dinv,
                                                   const int* __restrict__ row_ptr,
                                                   const int* __restrict__ col,
                                                   ush* __restrict__ axs, int n) {
  int lane = threadIdx.x & 63;
  int g = lane >> 4, fl = lane & 15;
  int i = blockIdx.x * 4 + (threadIdx.x >> 6);
  if (i >= n) return;
  int e0 = row_ptr[i], e1 = row_ptr[i + 1];
  float4 acc = make_float4(0.f, 0.f, 0.f, 0.f);
  float4 acc2 = make_float4(0.f, 0.f, 0.f, 0.f);
  int e = e0;
  for (; e + 8 <= e1; e += 8) {
    int c0 = col[e + g], c1 = col[e + 4 + g];
    ushort4 u0 = *(const ushort4*)&xs[(size_t)c0 * 64 + fl * 4];
    ushort4 u1 = *(const ushort4*)&xs[(size_t)c1 * 64 + fl * 4];
    acc.x += bf2f(u0.x);  acc.y += bf2f(u0.y);  acc.z += bf2f(u0.z);  acc.w += bf2f(u0.w);
    acc2.x += bf2f(u1.x); acc2.y += bf2f(u1.y); acc2.z += bf2f(u1.z); acc2.w += bf2f(u1.w);
  }
  for (; e < e1; e += 4) {
    int eg = e + g;
    bool valid = eg < e1;
    int c = col[valid ? eg : e];
    ushort4 u = *(const ushort4*)&xs[(size_t)c * 64 + fl * 4];
    float msk = valid ? 1.f : 0.f;
    acc.x = fmaf(msk, bf2f(u.x), acc.x);
    acc.y = fmaf(msk, bf2f(u.y), acc.y);
    acc.z = fmaf(msk, bf2f(u.z), acc.z);
    acc.w = fmaf(msk, bf2f(u.w), acc.w);
  }
  acc.x += acc2.x; acc.y += acc2.y; acc.z += acc2.z; acc.w += acc2.w;
  acc.x += __shfl_xor(acc.x, 16); acc.y += __shfl_xor(acc.y, 16);
  acc.z += __shfl_xor(acc.z, 16); acc.w += __shfl_xor(acc.w, 16);
  acc.x += __shfl_xor(acc.x, 32); acc.y += __shfl_xor(acc.y, 32);
  acc.z += __shfl_xor(acc.z, 32); acc.w += __shfl_xor(acc.w, 32);
  if (g == 0) {
    ushort4 us = *(const ushort4*)&xs[(size_t)i * 64 + fl * 4];
    float di = dinv[i];
    ushort4 o;
    o.x = f2bf(di * (acc.x + bf2f(us.x)));
    o.y = f2bf(di * (acc.y + bf2f(us.y)));
    o.z = f2bf(di * (acc.z + bf2f(us.z)));
    o.w = f2bf(di * (acc.w + bf2f(us.w)));
    *(ushort4*)&axs[(size_t)i * 64 + fl * 4] = o;
  }
}

// out[i,:] = x[i,:] + b2 + dinv[i] * ( sum h2s[s,:] + h2s[i,:] )
__global__ __launch_bounds__(256) void agg2_kernel(const ush* __restrict__ h2s,
                                                   const float* __restrict__ dinv,
                                                   const int* __restrict__ row_ptr,
                                                   const int* __restrict__ col,
                                                   const float* __restrict__ b,
                                                   const float* __restrict__ x,
                                                   float* __restrict__ out, int n) {
  int lane = threadIdx.x & 63;
  int g = lane >> 4, fl = lane & 15;
  int i = blockIdx.x * 4 + (threadIdx.x >> 6);
  if (i >= n) return;
  int e0 = row_ptr[i], e1 = row_ptr[i + 1];
  float4 acc = make_float4(0.f, 0.f, 0.f, 0.f);
  float4 acc2 = make_float4(0.f, 0.f, 0.f, 0.f);
  int e = e0;
  for (; e + 8 <= e1; e += 8) {
    int c0 = col[e + g], c1 = col[e + 4 + g];
    ushort4 u0 = *(const ushort4*)&h2s[(size_t)c0 * 64 + fl * 4];
    ushort4 u1 = *(const ushort4*)&h2s[(size_t)c1 * 64 + fl * 4];
    acc.x += bf2f(u0.x);  acc.y += bf2f(u0.y);  acc.z += bf2f(u0.z);  acc.w += bf2f(u0.w);
    acc2.x += bf2f(u1.x); acc2.y += bf2f(u1.y); acc2.z += bf2f(u1.z); acc2.w += bf2f(u1.w);
  }
  for (; e < e1; e += 4) {
    int eg = e + g;
    bool valid = eg < e1;
    int c = col[valid ? eg : e];
    ushort4 u = *(const ushort4*)&h2s[(size_t)c * 64 + fl * 4];
    float msk = valid ? 1.f : 0.f;
    acc.x = fmaf(msk, bf2f(u.x), acc.x);
    acc.y = fmaf(msk, bf2f(u.y), acc.y);
    acc.z = fmaf(msk, bf2f(u.z), acc.z);
    acc.w = fmaf(msk, bf2f(u.w), acc.w);
  }
  acc.x += acc2.x; acc.y += acc2.y; acc.z += acc2.z; acc.w += acc2.w;
  acc.x += __shfl_xor(acc.x, 16); acc.y += __shfl_xor(acc.y, 16);
  acc.z += __shfl_xor(acc.z, 16); acc.w += __shfl_xor(acc.w, 16);
  acc.x += __shfl_xor(acc.x, 32); acc.y += __shfl_xor(acc.y, 32);
  acc.z += __shfl_xor(acc.z, 32); acc.w += __shfl_xor(acc.w, 32);
  if (g == 0) {
    ushort4 us = *(const ushort4*)&h2s[(size_t)i * 64 + fl * 4];
    float di = dinv[i];
    float4 xr = *(const float4*)&x[(size_t)i * 64 + fl * 4];
    float4 bb = *(const float4*)&b[fl * 4];
    float4 o;
    o.x = xr.x + bb.x + di * (acc.x + bf2f(us.x));
    o.y = xr.y + bb.y + di * (acc.y + bf2f(us.y));
    o.z = xr.z + bb.z + di * (acc.z + bf2f(us.z));
    o.w = xr.w + bb.w + di * (acc.w + bf2f(us.w));
    *(float4*)&out[(size_t)i * 64 + fl * 4] = o;
  }
}

// ---------------- GEMMs via MFMA; W staged from immutable d_in into LDS ----------------
// A-frag: lane holds A[lane&15][kq*8..+8] (contiguous global); B-frag from LDS
// wl[j][k] (padded rows), same k-permutation as A so the dot is exact.
// D: col=lane&15, row=kq*4+reg (m89-verified).

#define P1 88    // w1 LDS row length in bf16 (64 data + 24 pad -> 176B, 2-way free)
#define P2 136   // w2 LDS row length in bf16 (128 data + 8 pad -> 272B, 2-way free)

// y1[n,128] = bf16( leaky(axs[n,64] @ W1 + b1) )
__global__ __launch_bounds__(256) void gemm1_mfma(const ush* __restrict__ axs,
                                                  const float* __restrict__ W,
                                                  const float* __restrict__ b,
                                                  ush* __restrict__ y1, int n) {
  __shared__ ush wl[128 * P1];   // 22.5 KB
  int t = threadIdx.x;
  for (int idx = t; idx < 128 * 64; idx += 256) {
    int j = idx >> 6, k = idx & 63;
    wl[j * P1 + k] = f2bf(W[k * 128 + j]);
  }
  __syncthreads();
  int lane = t & 63;
  int m = lane & 15, kq = lane >> 4;
  int ntiles = (n + 15) >> 4;
  for (int wid = blockIdx.x * 4 + (t >> 6); wid < ntiles; wid += gridDim.x * 4) {
    int node0 = wid << 4;
    int arow = min(node0 + m, n - 1);
    bf8v a0 = *(const bf8v*)&axs[(size_t)arow * 64 + kq * 8];        // k 0..31
    bf8v a1 = *(const bf8v*)&axs[(size_t)arow * 64 + 32 + kq * 8];   // k 32..63
#pragma unroll
    for (int j0 = 0; j0 < 128; j0 += 16) {
      const ush* wt = &wl[(j0 + m) * P1 + kq * 8];
      bf8v b0 = *(const bf8v*)wt;
      bf8v b1 = *(const bf8v*)(wt + 32);
      f4v acc = {0.f, 0.f, 0.f, 0.f};
      acc = __builtin_amdgcn_mfma_f32_16x16x32_bf16(a0, b0, acc, 0, 0, 0);
      acc = __builtin_amdgcn_mfma_f32_16x16x32_bf16(a1, b1, acc, 0, 0, 0);
      float bias = b[j0 + m];
#pragma unroll
      for (int r = 0; r < 4; ++r) {
        int orow = node0 + kq * 4 + r;
        if (orow < n) {
          float s = acc[r] + bias;
          s = (s >= 0.f) ? s : NEG * s;
          y1[(size_t)orow * 128 + j0 + m] = f2bf(s);
        }
      }
    }
  }
}

// h2s[n,64] = bf16( dinv ⊙ (y1[n,128] @ W2) )
__global__ __launch_bounds__(256) void gemm2_mfma(const ush* __restrict__ y1,
                                                  const float* __restrict__ W,
                                                  const float* __restrict__ dinv,
                                                  ush* __restrict__ h2s, int n) {
  __shared__ ush wl[64 * P2];   // 17.4 KB
  int t = threadIdx.x;
  for (int idx = t; idx < 64 * 128; idx += 256) {
    int j = idx >> 7, k = idx & 127;
    wl[j * P2 + k] = f2bf(W[k * 64 + j]);
  }
  __syncthreads();
  int lane = t & 63;
  int m = lane & 15, kq = lane >> 4;
  int ntiles = (n + 15) >> 4;
  for (int wid = blockIdx.x * 4 + (t >> 6); wid < ntiles; wid += gridDim.x * 4) {
    int node0 = wid << 4;
    int arow = min(node0 + m, n - 1);
    const ush* ap = &y1[(size_t)arow * 128 + kq * 8];
    bf8v a0 = *(const bf8v*)(ap);
    bf8v a1 = *(const bf8v*)(ap + 32);
    bf8v a2 = *(const bf8v*)(ap + 64);
    bf8v a3 = *(const bf8v*)(ap + 96);
    float dv[4];
#pragma unroll
    for (int r = 0; r < 4; ++r) dv[r] = dinv[min(node0 + kq * 4 + r, n - 1)];
#pragma unroll
    for (int j0 = 0; j0 < 64; j0 += 16) {
      const ush* wt = &wl[(j0 + m) * P2 + kq * 8];
      f4v acc = {0.f, 0.f, 0.f, 0.f};
      acc = __builtin_amdgcn_mfma_f32_16x16x32_bf16(a0, *(const bf8v*)(wt), acc, 0, 0, 0);
      acc = __builtin_amdgcn_mfma_f32_16x16x32_bf16(a1, *(const bf8v*)(wt + 32), acc, 0, 0, 0);
      acc = __builtin_amdgcn_mfma_f32_16x16x32_bf16(a2, *(const bf8v*)(wt + 64), acc, 0, 0, 0);
      acc = __builtin_amdgcn_mfma_f32_16x16x32_bf16(a3, *(const bf8v*)(wt + 96), acc, 0, 0, 0);
#pragma unroll
      for (int r = 0; r < 4; ++r) {
        int orow = node0 + kq * 4 + r;
        if (orow < n) h2s[(size_t)orow * 64 + j0 + m] = f2bf(acc[r] * dv[r]);
      }
    }
  }
}

// ---------------- launch ----------------

extern "C" void kernel_launch(void* const* d_in, const int* in_sizes, int n_in,
                              void* d_out, int out_size, void* d_ws, size_t ws_size,
                              hipStream_t stream) {
  const int n = in_sizes[0] / 64;   // 50000
  const int E = in_sizes[5] / 2;    // 800000

  const float* x  = (const float*)d_in[0];
  const float* W1 = (const float*)d_in[1];
  const float* b1 = (const float*)d_in[2];
  const float* W2 = (const float*)d_in[3];
  const float* b2 = (const float*)d_in[4];
  const int* edge = (const int*)d_in[5];
  const int* esrc = edge;
  const int* edst = edge + E;

  char* ws = (char*)d_ws;
  size_t o = 0;
  auto take = [&](size_t bytes) -> void* {
    void* p = ws + o;
    o += (bytes + 255) & ~(size_t)255;
    return p;
  };
  const int NBUCK = (n + 127) >> 7;  // 391
  int*   bcnt    = (int*)take(512 * 4);
  int*   bbase   = (int*)take(513 * 4);
  int*   bnext   = (int*)take(512 * 4);
  int*   row_ptr = (int*)take((size_t)(n + 1) * 4);
  float* dinv    = (float*)take((size_t)n * 4);
  uint2* tmp     = (uint2*)take((size_t)E * 8);
  int*   col     = (int*)take((size_t)E * 4);
  ush*   xs      = (ush*)take((size_t)n * 64 * 2);
  ush*   axs     = (ush*)take((size_t)n * 64 * 2);
  ush*   y1      = (ush*)take((size_t)n * 128 * 2);
  ush*   h2s     = xs;  // xs dead after aggx; reuse

  hipMemsetAsync(bcnt, 0, 512 * 4, stream);

  int pb = (E + CHUNK - 1) / CHUNK;  // 196
  bucket_count<<<pb, 256, 0, stream>>>(edst, bcnt, E);
  bucket_scan<<<1, 256, 0, stream>>>(bcnt, bbase, bnext, E);
  partition_kernel<<<pb, 256, 0, stream>>>(esrc, edst, bnext, tmp, E);
  csr_finalize<<<NBUCK, 256, 0, stream>>>(tmp, bbase, row_ptr, dinv, col, n, E);

  xscale_kernel<<<(n * 16 + 255) / 256, 256, 0, stream>>>(x, dinv, xs, n * 16);
  aggx_kernel<<<(n + 3) / 4, 256, 0, stream>>>(xs, dinv, row_ptr, col, axs, n);

  gemm1_mfma<<<512, 256, 0, stream>>>(axs, W1, b1, y1, n);
  gemm2_mfma<<<512, 256, 0, stream>>>(y1, W2, dinv, h2s, n);

  agg2_kernel<<<(n + 3) / 4, 256, 0, stream>>>(h2s, dinv, row_ptr, col, b2, x,
                                               (float*)d_out, n);
}